// Round 7
// baseline (527.677 us; speedup 1.0000x reference)
//
#include <hip/hip_runtime.h>

// ---------------------------------------------------------------------------
// TransformerBlock: B=4, S=2048, D=768, H=12, DK=64, DFF=3072, fp32 in/out.
// bf16 MFMA 16x16x32; fp32 LN/softmax/residuals.
// Round 7: attention back to 1 q-tile(128)/block, 768 blocks, heavy-first
// (R6's paired 384-block grid starved the CUs: 8.7% occupancy, 151us).
// ---------------------------------------------------------------------------

typedef __attribute__((ext_vector_type(8))) short bf16x8;
typedef __attribute__((ext_vector_type(4))) float f32x4;
typedef __attribute__((ext_vector_type(4))) unsigned short us4;

#define B_ 4
#define S_ 2048
#define D_ 768
#define H_ 12
#define DK_ 64
#define DFF_ 3072

#define GLOAD_LDS16(g, l)                                                              \
  __builtin_amdgcn_global_load_lds(                                                    \
      (const __attribute__((address_space(1))) unsigned int*)(g),                      \
      (__attribute__((address_space(3))) unsigned int*)(l), 16, 0, 0)

__device__ inline float fast_exp2(float x) { return __builtin_amdgcn_exp2f(x); }

__device__ inline unsigned short f2bf(float f) {
  union { float f; unsigned int u; } v; v.f = f;
  unsigned int r = v.u + 0x7fffu + ((v.u >> 16) & 1u);  // RTN-even
  return (unsigned short)(r >> 16);
}
__device__ inline unsigned short f2bf_trunc(float f) {  // for P in [0,1]
  union { float f; unsigned int u; } v; v.f = f;
  return (unsigned short)(v.u >> 16);
}
__device__ inline float bf2f(unsigned short h) {
  union { unsigned int u; float f; } v; v.u = ((unsigned int)h) << 16;
  return v.f;
}

// --------------------- tiled transpose+convert (batched) -------------------
struct TransArgs { const float* s[4]; unsigned short* d[4]; };

__global__ __launch_bounds__(256) void transpose_cvt(TransArgs a, int K, int N) {
  const float* __restrict__ src = a.s[blockIdx.z];
  unsigned short* __restrict__ dst = a.d[blockIdx.z];
  __shared__ float tile[32][33];
  const int k0 = blockIdx.x * 32, n0 = blockIdx.y * 32;
  const int c = threadIdx.x & 31, r = threadIdx.x >> 5;
#pragma unroll
  for (int rr = 0; rr < 32; rr += 8)
    tile[r + rr][c] = src[(size_t)(k0 + r + rr) * N + n0 + c];
  __syncthreads();
#pragma unroll
  for (int rr = 0; rr < 32; rr += 8)
    dst[(size_t)(n0 + r + rr) * K + k0 + c] = f2bf(tile[c][r + rr]);
}

// ---------------------- LayerNorm: one wave per row ------------------------
__global__ __launch_bounds__(256) void ln_kernel(
    const float* __restrict__ x, const float* __restrict__ gw,
    const float* __restrict__ bw, unsigned short* __restrict__ out) {
  const int row = blockIdx.x * 4 + (threadIdx.x >> 6);
  const int lane = threadIdx.x & 63;
  const float4* xr = (const float4*)(x + (size_t)row * D_);
  float4 v[3]; float s = 0.f, ss = 0.f;
#pragma unroll
  for (int i = 0; i < 3; ++i) {
    v[i] = xr[lane + i * 64];
    s += v[i].x + v[i].y + v[i].z + v[i].w;
    ss += v[i].x * v[i].x + v[i].y * v[i].y + v[i].z * v[i].z + v[i].w * v[i].w;
  }
#pragma unroll
  for (int off = 32; off; off >>= 1) { s += __shfl_xor(s, off); ss += __shfl_xor(ss, off); }
  const float mu = s * (1.f / D_);
  const float rstd = rsqrtf(ss * (1.f / D_) - mu * mu + 1e-5f);
#pragma unroll
  for (int i = 0; i < 3; ++i) {
    const int c = (lane + i * 64) * 4;
    us4 o4;
    o4.x = f2bf((v[i].x - mu) * rstd * gw[c + 0] + bw[c + 0]);
    o4.y = f2bf((v[i].y - mu) * rstd * gw[c + 1] + bw[c + 1]);
    o4.z = f2bf((v[i].z - mu) * rstd * gw[c + 2] + bw[c + 2]);
    o4.w = f2bf((v[i].w - mu) * rstd * gw[c + 3] + bw[c + 3]);
    *(us4*)&out[(size_t)row * D_ + c] = o4;
  }
}

// ------------------------------ GEMM (A @ Bt^T) ----------------------------
// 128x128 tile, 4 waves 64x64, BK=64 (2 MFMA k-steps per barrier pair).
constexpr int EP_RESID = 0;
constexpr int EP_QKV   = 1;

template <int EP>
__global__ __launch_bounds__(256) void gemm_bt(
    const unsigned short* __restrict__ A, const unsigned short* __restrict__ Bt,
    int M, int N, int K,
    float* __restrict__ outf, const float* __restrict__ resid,
    unsigned short* __restrict__ qo, unsigned short* __restrict__ ko,
    unsigned short* __restrict__ vto) {
  __shared__ __align__(16) unsigned short As[128 * 64];
  __shared__ __align__(16) unsigned short Bs[128 * 64];
  const int tid = threadIdx.x;
  const int lane = tid & 63, w = tid >> 6;
  const int wm = w >> 1, wn = w & 1;
  const int g = lane >> 4, l15 = lane & 15;
  const int m0 = blockIdx.x * 128, n0 = blockIdx.y * 128;

  f32x4 acc[4][4];
  const f32x4 z = {0.f, 0.f, 0.f, 0.f};
#pragma unroll
  for (int i = 0; i < 4; ++i)
#pragma unroll
    for (int j = 0; j < 4; ++j) acc[i][j] = z;

  for (int k0 = 0; k0 < K; k0 += 64) {
#pragma unroll
    for (int it = 0; it < 4; ++it) {
      const int idx = it * 256 + tid;
      const int rr = idx >> 3, cc = (idx & 7) ^ (rr & 7);
      const unsigned baseo =
          __builtin_amdgcn_readfirstlane((unsigned)((it * 256 + w * 64) * 8));
      GLOAD_LDS16(A + (size_t)(m0 + rr) * K + k0 + cc * 8, As + baseo);
      GLOAD_LDS16(Bt + (size_t)(n0 + rr) * K + k0 + cc * 8, Bs + baseo);
    }
    __syncthreads();
#pragma unroll
    for (int kh = 0; kh < 2; ++kh) {
      bf16x8 af[4], bfr[4];
#pragma unroll
      for (int i = 0; i < 4; ++i) {
        const int rA = wm * 64 + i * 16 + l15;
        af[i] = *(const bf16x8*)&As[rA * 64 + (((kh * 4 + g) ^ (rA & 7)) * 8)];
      }
#pragma unroll
      for (int j = 0; j < 4; ++j) {
        const int rB = wn * 64 + j * 16 + l15;
        bfr[j] = *(const bf16x8*)&Bs[rB * 64 + (((kh * 4 + g) ^ (rB & 7)) * 8)];
      }
#pragma unroll
      for (int i = 0; i < 4; ++i)
#pragma unroll
        for (int j = 0; j < 4; ++j)
          acc[i][j] = __builtin_amdgcn_mfma_f32_16x16x32_bf16(af[i], bfr[j], acc[i][j], 0, 0, 0);
    }
    __syncthreads();
  }

  // Epilogue. C/D: row = 4*(lane>>4)+reg, col = lane&15 (m89/m91).
  const float QSC = 0.125f * 1.44269504088896f;  // softmax scale * log2(e)
#pragma unroll
  for (int i = 0; i < 4; ++i) {
#pragma unroll
    for (int j = 0; j < 4; ++j) {
      const int cl = wn * 64 + j * 16 + l15;
      const int col = n0 + cl;
#pragma unroll
      for (int r = 0; r < 4; ++r) {
        const int row = m0 + wm * 64 + i * 16 + 4 * g + r;
        const float v = acc[i][j][r];
        if constexpr (EP == EP_RESID) {
          outf[(size_t)row * N + col] = v + resid[(size_t)row * N + col];
        } else {
          const int b = row >> 11, s = row & (S_ - 1);
          if (col < D_) {
            const int hh = col >> 6, dk = col & 63;
            qo[(((size_t)b * H_ + hh) * S_ + s) * DK_ + dk] = f2bf(v * QSC);
          } else if (col < 2 * D_) {
            const int c2 = col - D_, hh = c2 >> 6, dk = c2 & 63;
            ko[(((size_t)b * H_ + hh) * S_ + s) * DK_ + dk] = f2bf(v);
          } else {
            const int c2 = col - 2 * D_, hh = c2 >> 6, dk = c2 & 63;
            vto[(((size_t)b * H_ + hh) * DK_ + dk) * S_ + s] = f2bf(v);
          }
        }
      }
    }
  }
}

// --------------------------- causal flash attention ------------------------
// One 128-row q-tile per block (2 subtiles of 64 per wave), K-tile 128.
// Grid 16x48, heavy tiles first (t = 15 - blockIdx.x).
template <int NT, bool MASK>
__device__ __forceinline__ void attn_tile(
    const unsigned short* Ks, const unsigned short* Vs, unsigned short* Psw,
    const bf16x8& aq0, const bf16x8& aq1,
    f32x4 (&o)[4], float (&m_i)[4], float (&l_p)[4],
    int colbase, int rowg, int l15, int g) {
  const f32x4 z = {0.f, 0.f, 0.f, 0.f};
  f32x4 sc[NT];
#pragma unroll
  for (int nt = 0; nt < NT; ++nt) {
    const int rk = nt * 16 + l15;
    bf16x8 b0 = *(const bf16x8*)&Ks[rk * 64 + ((g ^ (rk & 7)) * 8)];
    bf16x8 b1 = *(const bf16x8*)&Ks[rk * 64 + (((4 + g) ^ (rk & 7)) * 8)];
    f32x4 t = __builtin_amdgcn_mfma_f32_16x16x32_bf16(aq0, b0, z, 0, 0, 0);
    sc[nt] = __builtin_amdgcn_mfma_f32_16x16x32_bf16(aq1, b1, t, 0, 0, 0);
  }
#pragma unroll
  for (int r = 0; r < 4; ++r) {
    const int row = rowg + r;
    float best = -3.0e38f;
#pragma unroll
    for (int nt = 0; nt < NT; ++nt) {
      float v = sc[nt][r];
      if (MASK) {
        const int col = colbase + nt * 16 + l15;
        v = (col <= row) ? v : -3.0e38f;
        sc[nt][r] = v;
      }
      best = fmaxf(best, v);
    }
    best = fmaxf(best, __shfl_xor(best, 1));
    best = fmaxf(best, __shfl_xor(best, 2));
    best = fmaxf(best, __shfl_xor(best, 4));
    best = fmaxf(best, __shfl_xor(best, 8));
    const float mnew = fmaxf(m_i[r], best);
    const float alpha = fast_exp2(m_i[r] - mnew);
    m_i[r] = mnew;
    float ls = 0.f;
#pragma unroll
    for (int nt = 0; nt < NT; ++nt) {
      const float p = fast_exp2(sc[nt][r] - mnew);
      sc[nt][r] = p;
      ls += p;
    }
    l_p[r] = l_p[r] * alpha + ls;  // lane-partial; reduced in epilogue
#pragma unroll
    for (int d = 0; d < 4; ++d) o[d][r] *= alpha;
  }
#pragma unroll
  for (int nt = 0; nt < NT; ++nt)
#pragma unroll
    for (int r = 0; r < 4; ++r)
      Psw[(4 * g + r) * 136 + nt * 16 + l15] = f2bf_trunc(sc[nt][r]);
  // PV (same-wave LDS write->read: no barrier)
#pragma unroll
  for (int ks = 0; ks < NT / 2; ++ks) {
    bf16x8 ap = *(const bf16x8*)&Psw[l15 * 136 + ks * 32 + 8 * g];
#pragma unroll
    for (int nt2 = 0; nt2 < 4; ++nt2) {
      const int rv = nt2 * 16 + l15;
      bf16x8 bv = *(const bf16x8*)&Vs[rv * 128 + (((ks * 4 + g) ^ (rv & 15)) * 8)];
      o[nt2] = __builtin_amdgcn_mfma_f32_16x16x32_bf16(ap, bv, o[nt2], 0, 0, 0);
    }
  }
}

__global__ __launch_bounds__(256) void attn_kernel(
    const unsigned short* __restrict__ q, const unsigned short* __restrict__ k,
    const unsigned short* __restrict__ vt, unsigned short* __restrict__ outp) {
  __shared__ __align__(16) unsigned short Ks[128 * 64];
  __shared__ __align__(16) unsigned short Vs[64 * 128];
  __shared__ __align__(16) unsigned short Ps[4][16 * 136];
  const int t = 15 - blockIdx.x;               // heavy tiles dispatch first
  const int bh = blockIdx.y;
  const int b = bh / H_, h = bh % H_;
  const unsigned short* qp = q + (size_t)bh * S_ * DK_;
  const unsigned short* kp = k + (size_t)bh * S_ * DK_;
  const unsigned short* vp = vt + (size_t)bh * DK_ * S_;
  const int tid = threadIdx.x, lane = tid & 63, w = tid >> 6;
  const int g = lane >> 4, l15 = lane & 15;

  bf16x8 aq[2][2];
#pragma unroll
  for (int sub = 0; sub < 2; ++sub) {
    const int qrow = t * 128 + sub * 64 + w * 16 + l15;
    aq[sub][0] = *(const bf16x8*)&qp[(size_t)qrow * DK_ + 8 * g];
    aq[sub][1] = *(const bf16x8*)&qp[(size_t)qrow * DK_ + 32 + 8 * g];
  }
  f32x4 o[2][4];
  float m_i[2][4], l_p[2][4];
  const f32x4 z = {0.f, 0.f, 0.f, 0.f};
#pragma unroll
  for (int sub = 0; sub < 2; ++sub)
#pragma unroll
    for (int r = 0; r < 4; ++r) {
      m_i[sub][r] = -3.0e38f; l_p[sub][r] = 0.f; o[sub][r] = z;
    }
  const int rowg0 = t * 128 + w * 16 + 4 * g;
  const int nkt = t + 1;

  for (int kt = 0; kt < nkt; ++kt) {
#pragma unroll
    for (int it = 0; it < 4; ++it) {
      const int idx = it * 256 + tid;
      const int rK = idx >> 3, cbK = (idx & 7) ^ (rK & 7);
      const int rV = idx >> 4, cbV = (idx & 15) ^ (rV & 15);
      const unsigned baseo =
          __builtin_amdgcn_readfirstlane((unsigned)((it * 256 + w * 64) * 8));
      GLOAD_LDS16(kp + ((size_t)kt * 128 + rK) * DK_ + cbK * 8, Ks + baseo);
      GLOAD_LDS16(vp + (size_t)rV * S_ + kt * 128 + cbV * 8, Vs + baseo);
    }
    __syncthreads();
    const int colbase = kt * 128;
    if (kt != nkt - 1) {
      attn_tile<8, false>(Ks, Vs, &Ps[w][0], aq[0][0], aq[0][1], o[0], m_i[0], l_p[0], colbase, rowg0, l15, g);
      attn_tile<8, false>(Ks, Vs, &Ps[w][0], aq[1][0], aq[1][1], o[1], m_i[1], l_p[1], colbase, rowg0 + 64, l15, g);
    } else {
      attn_tile<4, true>(Ks, Vs, &Ps[w][0], aq[0][0], aq[0][1], o[0], m_i[0], l_p[0], colbase, rowg0, l15, g);
      attn_tile<8, true>(Ks, Vs, &Ps[w][0], aq[1][0], aq[1][1], o[1], m_i[1], l_p[1], colbase, rowg0 + 64, l15, g);
    }
    __syncthreads();
  }
#pragma unroll
  for (int sub = 0; sub < 2; ++sub) {
#pragma unroll
    for (int r = 0; r < 4; ++r) {
      float ls = l_p[sub][r];
      ls += __shfl_xor(ls, 1);
      ls += __shfl_xor(ls, 2);
      ls += __shfl_xor(ls, 4);
      ls += __shfl_xor(ls, 8);
      l_p[sub][r] = 1.0f / ls;
    }
#pragma unroll
    for (int nt2 = 0; nt2 < 4; ++nt2)
#pragma unroll
      for (int r = 0; r < 4; ++r) {
        const int s = t * 128 + sub * 64 + w * 16 + 4 * g + r;
        outp[((size_t)b * S_ + s) * D_ + h * 64 + nt2 * 16 + l15] =
            f2bf(o[sub][nt2][r] * l_p[sub][r]);
      }
  }
}

// ---------------------- fused Wg GEMM + bias + GeGLU -----------------------
// Dual accumulators (val+gate), BK=64.
__global__ __launch_bounds__(256, 2) void geglu_gemm(
    const unsigned short* __restrict__ A, const unsigned short* __restrict__ Bt,
    const float* __restrict__ bias, unsigned short* __restrict__ ff) {
  __shared__ __align__(16) unsigned short As[128 * 64];
  __shared__ __align__(16) unsigned short Bsv[128 * 64];
  __shared__ __align__(16) unsigned short Bsg[128 * 64];
  const int tid = threadIdx.x, lane = tid & 63, w = tid >> 6;
  const int wm = w >> 1, wn = w & 1, g = lane >> 4, l15 = lane & 15;
  const int m0 = blockIdx.x * 128, n0 = blockIdx.y * 128;
  const f32x4 z = {0.f, 0.f, 0.f, 0.f};
  f32x4 av[4][4], ag[4][4];
#pragma unroll
  for (int i = 0; i < 4; ++i)
#pragma unroll
    for (int j = 0; j < 4; ++j) { av[i][j] = z; ag[i][j] = z; }

  const unsigned short* Btg = Bt + (size_t)DFF_ * D_;

  for (int k0 = 0; k0 < D_; k0 += 64) {
#pragma unroll
    for (int it = 0; it < 4; ++it) {
      const int idx = it * 256 + tid;
      const int rr = idx >> 3, cc = (idx & 7) ^ (rr & 7);
      const unsigned baseo =
          __builtin_amdgcn_readfirstlane((unsigned)((it * 256 + w * 64) * 8));
      GLOAD_LDS16(A + (size_t)(m0 + rr) * D_ + k0 + cc * 8, As + baseo);
      GLOAD_LDS16(Bt + (size_t)(n0 + rr) * D_ + k0 + cc * 8, Bsv + baseo);
      GLOAD_LDS16(Btg + (size_t)(n0 + rr) * D_ + k0 + cc * 8, Bsg + baseo);
    }
    __syncthreads();
#pragma unroll
    for (int kh = 0; kh < 2; ++kh) {
      bf16x8 af[4], bv[4], bgf[4];
#pragma unroll
      for (int i = 0; i < 4; ++i) {
        const int rA = wm * 64 + i * 16 + l15;
        af[i] = *(const bf16x8*)&As[rA * 64 + (((kh * 4 + g) ^ (rA & 7)) * 8)];
      }
#pragma unroll
      for (int j = 0; j < 4; ++j) {
        const int rB = wn * 64 + j * 16 + l15;
        const int sw = ((kh * 4 + g) ^ (rB & 7)) * 8;
        bv[j] = *(const bf16x8*)&Bsv[rB * 64 + sw];
        bgf[j] = *(const bf16x8*)&Bsg[rB * 64 + sw];
      }
#pragma unroll
      for (int i = 0; i < 4; ++i)
#pragma unroll
        for (int j = 0; j < 4; ++j) {
          av[i][j] = __builtin_amdgcn_mfma_f32_16x16x32_bf16(af[i], bv[j], av[i][j], 0, 0, 0);
          ag[i][j] = __builtin_amdgcn_mfma_f32_16x16x32_bf16(af[i], bgf[j], ag[i][j], 0, 0, 0);
        }
    }
    __syncthreads();
  }

#pragma unroll
  for (int i = 0; i < 4; ++i)
#pragma unroll
    for (int j = 0; j < 4; ++j) {
      const int cl = wn * 64 + j * 16 + l15;
      const float bv_ = bias[n0 + cl], bg_ = bias[DFF_ + n0 + cl];
#pragma unroll
      for (int r = 0; r < 4; ++r) {
        const int rl = wm * 64 + i * 16 + 4 * g + r;
        const float val = av[i][j][r] + bv_;
        const float gate = ag[i][j][r] + bg_;
        const float ge = 0.5f * gate * (1.0f + erff(gate * 0.70710678118654752f));
        ff[(size_t)(m0 + rl) * DFF_ + n0 + cl] = f2bf(val * ge);
      }
    }
}

// ------------------------------- launcher ----------------------------------
extern "C" void kernel_launch(void* const* d_in, const int* in_sizes, int n_in,
                              void* d_out, int out_size, void* d_ws, size_t ws_size,
                              hipStream_t stream) {
  const float* x    = (const float*)d_in[0];
  const float* ln1g = (const float*)d_in[2];
  const float* ln1b = (const float*)d_in[3];
  const float* ln2g = (const float*)d_in[4];
  const float* ln2b = (const float*)d_in[5];
  const float* Wq   = (const float*)d_in[6];
  const float* Wk   = (const float*)d_in[7];
  const float* Wv   = (const float*)d_in[8];
  const float* Wo   = (const float*)d_in[9];
  const float* Wg   = (const float*)d_in[10];
  const float* bg   = (const float*)d_in[11];
  const float* Wout = (const float*)d_in[12];
  float* out = (float*)d_out;

  char* ws = (char*)d_ws;
  constexpr size_t SZ_WQKV = (size_t)3 * D_ * D_ * 2;
  constexpr size_t SZ_WO   = (size_t)D_ * D_ * 2;
  constexpr size_t SZ_WG   = (size_t)2 * DFF_ * D_ * 2;
  constexpr size_t SZ_WOUT = (size_t)D_ * DFF_ * 2;
  constexpr size_t SZ_ACT  = (size_t)B_ * S_ * D_ * 2;
  constexpr size_t OFF_WQKV = 0;
  constexpr size_t OFF_WO   = OFF_WQKV + SZ_WQKV;
  constexpr size_t OFF_WG   = OFF_WO + SZ_WO;
  constexpr size_t OFF_WOUT = OFF_WG + SZ_WG;
  constexpr size_t OFF_UNION = OFF_WOUT + SZ_WOUT;
  constexpr size_t OFF_H    = OFF_UNION;
  constexpr size_t OFF_Q    = OFF_UNION + SZ_ACT;
  constexpr size_t OFF_K    = OFF_UNION + 2 * SZ_ACT;
  constexpr size_t OFF_VT   = OFF_UNION + 3 * SZ_ACT;
  constexpr size_t OFF_FF   = OFF_UNION;               // ff overlays h/q/k/vt
  constexpr size_t OFF_ATTN = OFF_UNION + 4 * SZ_ACT;
  constexpr size_t OFF_X1   = OFF_ATTN + SZ_ACT;
  constexpr size_t OFF_H2   = OFF_X1 + (size_t)B_ * S_ * D_ * 4;

  unsigned short* wqkv_t = (unsigned short*)(ws + OFF_WQKV);
  unsigned short* wo_t   = (unsigned short*)(ws + OFF_WO);
  unsigned short* wg_t   = (unsigned short*)(ws + OFF_WG);
  unsigned short* wout_t = (unsigned short*)(ws + OFF_WOUT);
  unsigned short* h    = (unsigned short*)(ws + OFF_H);
  unsigned short* qb_  = (unsigned short*)(ws + OFF_Q);
  unsigned short* kb_  = (unsigned short*)(ws + OFF_K);
  unsigned short* vtb_ = (unsigned short*)(ws + OFF_VT);
  unsigned short* attn = (unsigned short*)(ws + OFF_ATTN);
  float*          x1   = (float*)(ws + OFF_X1);
  unsigned short* h2   = (unsigned short*)(ws + OFF_H2);
  unsigned short* ffb  = (unsigned short*)(ws + OFF_FF);

  {
    TransArgs a;
    a.s[0] = Wq; a.s[1] = Wk; a.s[2] = Wv; a.s[3] = Wo;
    a.d[0] = wqkv_t; a.d[1] = wqkv_t + (size_t)D_ * D_;
    a.d[2] = wqkv_t + (size_t)2 * D_ * D_; a.d[3] = wo_t;
    transpose_cvt<<<dim3(24, 24, 4), 256, 0, stream>>>(a, D_, D_);
    TransArgs agr; agr.s[0] = Wg; agr.d[0] = wg_t;
    agr.s[1] = agr.s[2] = agr.s[3] = Wg; agr.d[1] = agr.d[2] = agr.d[3] = wg_t;
    transpose_cvt<<<dim3(24, 192, 1), 256, 0, stream>>>(agr, D_, 2 * DFF_);
    TransArgs ao; ao.s[0] = Wout; ao.d[0] = wout_t;
    ao.s[1] = ao.s[2] = ao.s[3] = Wout; ao.d[1] = ao.d[2] = ao.d[3] = wout_t;
    transpose_cvt<<<dim3(96, 24, 1), 256, 0, stream>>>(ao, DFF_, D_);
  }

  ln_kernel<<<dim3(B_ * S_ / 4), 256, 0, stream>>>(x, ln1g, ln1b, h);
  gemm_bt<EP_QKV><<<dim3(64, 18), 256, 0, stream>>>(h, wqkv_t, B_ * S_, 3 * D_, D_,
                                                    nullptr, nullptr, qb_, kb_, vtb_);
  attn_kernel<<<dim3(16, B_ * H_), 256, 0, stream>>>(qb_, kb_, vtb_, attn);
  gemm_bt<EP_RESID><<<dim3(64, 6), 256, 0, stream>>>(attn, wo_t, B_ * S_, D_, D_,
                                                     x1, x, nullptr, nullptr, nullptr);
  ln_kernel<<<dim3(B_ * S_ / 4), 256, 0, stream>>>(x1, ln2g, ln2b, h2);
  geglu_gemm<<<dim3(64, 24), 256, 0, stream>>>(h2, wg_t, bg, ffb);
  gemm_bt<EP_RESID><<<dim3(64, 6), 256, 0, stream>>>(ffb, wout_t, B_ * S_, D_, DFF_,
                                                     out, x1, nullptr, nullptr, nullptr);
}

// Round 8
// 442.807 us; speedup vs baseline: 1.1917x; 1.1917x over previous
//
#include <hip/hip_runtime.h>

// ---------------------------------------------------------------------------
// TransformerBlock: B=4, S=2048, D=768, H=12, DK=64, DFF=3072, fp32 in/out.
// bf16 MFMA 16x16x32; fp32 LN/softmax/residuals.
// Round 8: attention reverted to uniform 17-tile pairing (R4 structure; R6/R7
// grids were capacity-bound with non-uniform/undersized blocks). Wo/Wout use
// 64x128 tiles (768 blocks) — 128x128 gave only 384 blocks = 1.5/CU.
// ---------------------------------------------------------------------------

typedef __attribute__((ext_vector_type(8))) short bf16x8;
typedef __attribute__((ext_vector_type(4))) float f32x4;
typedef __attribute__((ext_vector_type(4))) unsigned short us4;

#define B_ 4
#define S_ 2048
#define D_ 768
#define H_ 12
#define DK_ 64
#define DFF_ 3072

#define GLOAD_LDS16(g, l)                                                              \
  __builtin_amdgcn_global_load_lds(                                                    \
      (const __attribute__((address_space(1))) unsigned int*)(g),                      \
      (__attribute__((address_space(3))) unsigned int*)(l), 16, 0, 0)

__device__ inline float fast_exp2(float x) { return __builtin_amdgcn_exp2f(x); }

__device__ inline unsigned short f2bf(float f) {
  union { float f; unsigned int u; } v; v.f = f;
  unsigned int r = v.u + 0x7fffu + ((v.u >> 16) & 1u);  // RTN-even
  return (unsigned short)(r >> 16);
}
__device__ inline unsigned short f2bf_trunc(float f) {  // for P in [0,1]
  union { float f; unsigned int u; } v; v.f = f;
  return (unsigned short)(v.u >> 16);
}
__device__ inline float bf2f(unsigned short h) {
  union { unsigned int u; float f; } v; v.u = ((unsigned int)h) << 16;
  return v.f;
}

// --------------------- tiled transpose+convert (batched) -------------------
struct TransArgs { const float* s[4]; unsigned short* d[4]; };

__global__ __launch_bounds__(256) void transpose_cvt(TransArgs a, int K, int N) {
  const float* __restrict__ src = a.s[blockIdx.z];
  unsigned short* __restrict__ dst = a.d[blockIdx.z];
  __shared__ float tile[32][33];
  const int k0 = blockIdx.x * 32, n0 = blockIdx.y * 32;
  const int c = threadIdx.x & 31, r = threadIdx.x >> 5;
#pragma unroll
  for (int rr = 0; rr < 32; rr += 8)
    tile[r + rr][c] = src[(size_t)(k0 + r + rr) * N + n0 + c];
  __syncthreads();
#pragma unroll
  for (int rr = 0; rr < 32; rr += 8)
    dst[(size_t)(n0 + r + rr) * K + k0 + c] = f2bf(tile[c][r + rr]);
}

// ---------------------- LayerNorm: one wave per row ------------------------
__global__ __launch_bounds__(256) void ln_kernel(
    const float* __restrict__ x, const float* __restrict__ gw,
    const float* __restrict__ bw, unsigned short* __restrict__ out) {
  const int row = blockIdx.x * 4 + (threadIdx.x >> 6);
  const int lane = threadIdx.x & 63;
  const float4* xr = (const float4*)(x + (size_t)row * D_);
  float4 v[3]; float s = 0.f, ss = 0.f;
#pragma unroll
  for (int i = 0; i < 3; ++i) {
    v[i] = xr[lane + i * 64];
    s += v[i].x + v[i].y + v[i].z + v[i].w;
    ss += v[i].x * v[i].x + v[i].y * v[i].y + v[i].z * v[i].z + v[i].w * v[i].w;
  }
#pragma unroll
  for (int off = 32; off; off >>= 1) { s += __shfl_xor(s, off); ss += __shfl_xor(ss, off); }
  const float mu = s * (1.f / D_);
  const float rstd = rsqrtf(ss * (1.f / D_) - mu * mu + 1e-5f);
#pragma unroll
  for (int i = 0; i < 3; ++i) {
    const int c = (lane + i * 64) * 4;
    us4 o4;
    o4.x = f2bf((v[i].x - mu) * rstd * gw[c + 0] + bw[c + 0]);
    o4.y = f2bf((v[i].y - mu) * rstd * gw[c + 1] + bw[c + 1]);
    o4.z = f2bf((v[i].z - mu) * rstd * gw[c + 2] + bw[c + 2]);
    o4.w = f2bf((v[i].w - mu) * rstd * gw[c + 3] + bw[c + 3]);
    *(us4*)&out[(size_t)row * D_ + c] = o4;
  }
}

// ------------------------------ GEMM (A @ Bt^T) ----------------------------
// 128x128 tile, 4 waves 64x64, BK=64. Used for QKV (grid 64x18).
constexpr int EP_RESID = 0;
constexpr int EP_QKV   = 1;

template <int EP>
__global__ __launch_bounds__(256) void gemm_bt(
    const unsigned short* __restrict__ A, const unsigned short* __restrict__ Bt,
    int M, int N, int K,
    float* __restrict__ outf, const float* __restrict__ resid,
    unsigned short* __restrict__ qo, unsigned short* __restrict__ ko,
    unsigned short* __restrict__ vto) {
  __shared__ __align__(16) unsigned short As[128 * 64];
  __shared__ __align__(16) unsigned short Bs[128 * 64];
  const int tid = threadIdx.x;
  const int lane = tid & 63, w = tid >> 6;
  const int wm = w >> 1, wn = w & 1;
  const int g = lane >> 4, l15 = lane & 15;
  const int m0 = blockIdx.x * 128, n0 = blockIdx.y * 128;

  f32x4 acc[4][4];
  const f32x4 z = {0.f, 0.f, 0.f, 0.f};
#pragma unroll
  for (int i = 0; i < 4; ++i)
#pragma unroll
    for (int j = 0; j < 4; ++j) acc[i][j] = z;

  for (int k0 = 0; k0 < K; k0 += 64) {
#pragma unroll
    for (int it = 0; it < 4; ++it) {
      const int idx = it * 256 + tid;
      const int rr = idx >> 3, cc = (idx & 7) ^ (rr & 7);
      const unsigned baseo =
          __builtin_amdgcn_readfirstlane((unsigned)((it * 256 + w * 64) * 8));
      GLOAD_LDS16(A + (size_t)(m0 + rr) * K + k0 + cc * 8, As + baseo);
      GLOAD_LDS16(Bt + (size_t)(n0 + rr) * K + k0 + cc * 8, Bs + baseo);
    }
    __syncthreads();
#pragma unroll
    for (int kh = 0; kh < 2; ++kh) {
      bf16x8 af[4], bfr[4];
#pragma unroll
      for (int i = 0; i < 4; ++i) {
        const int rA = wm * 64 + i * 16 + l15;
        af[i] = *(const bf16x8*)&As[rA * 64 + (((kh * 4 + g) ^ (rA & 7)) * 8)];
      }
#pragma unroll
      for (int j = 0; j < 4; ++j) {
        const int rB = wn * 64 + j * 16 + l15;
        bfr[j] = *(const bf16x8*)&Bs[rB * 64 + (((kh * 4 + g) ^ (rB & 7)) * 8)];
      }
#pragma unroll
      for (int i = 0; i < 4; ++i)
#pragma unroll
        for (int j = 0; j < 4; ++j)
          acc[i][j] = __builtin_amdgcn_mfma_f32_16x16x32_bf16(af[i], bfr[j], acc[i][j], 0, 0, 0);
    }
    __syncthreads();
  }

  // Epilogue. C/D: row = 4*(lane>>4)+reg, col = lane&15 (m89/m91).
  const float QSC = 0.125f * 1.44269504088896f;  // softmax scale * log2(e)
#pragma unroll
  for (int i = 0; i < 4; ++i) {
#pragma unroll
    for (int j = 0; j < 4; ++j) {
      const int cl = wn * 64 + j * 16 + l15;
      const int col = n0 + cl;
#pragma unroll
      for (int r = 0; r < 4; ++r) {
        const int row = m0 + wm * 64 + i * 16 + 4 * g + r;
        const float v = acc[i][j][r];
        if constexpr (EP == EP_RESID) {
          outf[(size_t)row * N + col] = v + resid[(size_t)row * N + col];
        } else {
          const int b = row >> 11, s = row & (S_ - 1);
          if (col < D_) {
            const int hh = col >> 6, dk = col & 63;
            qo[(((size_t)b * H_ + hh) * S_ + s) * DK_ + dk] = f2bf(v * QSC);
          } else if (col < 2 * D_) {
            const int c2 = col - D_, hh = c2 >> 6, dk = c2 & 63;
            ko[(((size_t)b * H_ + hh) * S_ + s) * DK_ + dk] = f2bf(v);
          } else {
            const int c2 = col - 2 * D_, hh = c2 >> 6, dk = c2 & 63;
            vto[(((size_t)b * H_ + hh) * DK_ + dk) * S_ + s] = f2bf(v);
          }
        }
      }
    }
  }
}

// ------------------- GEMM 64x128 tile (narrow-N, more blocks) --------------
// BM=64, BN=128, BK=64; 4 waves each 64x32. Grid (M/64, N/128) = 768 blocks
// for N=768 — 128x128 tiling only gave 384 (=1.5 blocks/CU, half idle).
__global__ __launch_bounds__(256) void gemm_bt64(
    const unsigned short* __restrict__ A, const unsigned short* __restrict__ Bt,
    int M, int N, int K,
    float* __restrict__ outf, const float* __restrict__ resid) {
  __shared__ __align__(16) unsigned short As[64 * 64];
  __shared__ __align__(16) unsigned short Bs[128 * 64];
  const int tid = threadIdx.x;
  const int lane = tid & 63, w = tid >> 6;
  const int g = lane >> 4, l15 = lane & 15;
  const int m0 = blockIdx.x * 64, n0 = blockIdx.y * 128;

  f32x4 acc[4][2];
  const f32x4 z = {0.f, 0.f, 0.f, 0.f};
#pragma unroll
  for (int i = 0; i < 4; ++i) { acc[i][0] = z; acc[i][1] = z; }

  for (int k0 = 0; k0 < K; k0 += 64) {
#pragma unroll
    for (int it = 0; it < 2; ++it) {
      const int idx = it * 256 + tid;
      const int rr = idx >> 3, cc = (idx & 7) ^ (rr & 7);
      const unsigned baseo =
          __builtin_amdgcn_readfirstlane((unsigned)((it * 256 + w * 64) * 8));
      GLOAD_LDS16(A + (size_t)(m0 + rr) * K + k0 + cc * 8, As + baseo);
    }
#pragma unroll
    for (int it = 0; it < 4; ++it) {
      const int idx = it * 256 + tid;
      const int rr = idx >> 3, cc = (idx & 7) ^ (rr & 7);
      const unsigned baseo =
          __builtin_amdgcn_readfirstlane((unsigned)((it * 256 + w * 64) * 8));
      GLOAD_LDS16(Bt + (size_t)(n0 + rr) * K + k0 + cc * 8, Bs + baseo);
    }
    __syncthreads();
#pragma unroll
    for (int kh = 0; kh < 2; ++kh) {
      bf16x8 af[4], bfr[2];
#pragma unroll
      for (int i = 0; i < 4; ++i) {
        const int rA = i * 16 + l15;
        af[i] = *(const bf16x8*)&As[rA * 64 + (((kh * 4 + g) ^ (rA & 7)) * 8)];
      }
#pragma unroll
      for (int j = 0; j < 2; ++j) {
        const int rB = w * 32 + j * 16 + l15;
        bfr[j] = *(const bf16x8*)&Bs[rB * 64 + (((kh * 4 + g) ^ (rB & 7)) * 8)];
      }
#pragma unroll
      for (int i = 0; i < 4; ++i)
#pragma unroll
        for (int j = 0; j < 2; ++j)
          acc[i][j] = __builtin_amdgcn_mfma_f32_16x16x32_bf16(af[i], bfr[j], acc[i][j], 0, 0, 0);
    }
    __syncthreads();
  }

#pragma unroll
  for (int i = 0; i < 4; ++i)
#pragma unroll
    for (int j = 0; j < 2; ++j) {
      const int col = n0 + w * 32 + j * 16 + l15;
#pragma unroll
      for (int r = 0; r < 4; ++r) {
        const int row = m0 + i * 16 + 4 * g + r;
        outf[(size_t)row * N + col] = acc[i][j][r] + resid[(size_t)row * N + col];
      }
    }
}

// --------------------------- causal flash attention ------------------------
// R4 structure: 64-row q-subtiles, 128-key k-tiles; block pairs (pb, 31-pb)
// -> exactly 17 k-tile passes per block (uniform at capacity). exp2 softmax.
template <int NT, bool MASK>
__device__ __forceinline__ void attn_tile(
    const unsigned short* Ks, const unsigned short* Vs, unsigned short* Psw,
    const bf16x8& aq0, const bf16x8& aq1,
    f32x4 (&o)[4], float (&m_i)[4], float (&l_p)[4],
    int colbase, int rowg, int l15, int g) {
  const f32x4 z = {0.f, 0.f, 0.f, 0.f};
  f32x4 sc[NT];
#pragma unroll
  for (int nt = 0; nt < NT; ++nt) {
    const int rk = nt * 16 + l15;
    bf16x8 b0 = *(const bf16x8*)&Ks[rk * 64 + ((g ^ (rk & 7)) * 8)];
    bf16x8 b1 = *(const bf16x8*)&Ks[rk * 64 + (((4 + g) ^ (rk & 7)) * 8)];
    f32x4 t = __builtin_amdgcn_mfma_f32_16x16x32_bf16(aq0, b0, z, 0, 0, 0);
    sc[nt] = __builtin_amdgcn_mfma_f32_16x16x32_bf16(aq1, b1, t, 0, 0, 0);
  }
#pragma unroll
  for (int r = 0; r < 4; ++r) {
    const int row = rowg + r;
    float best = -3.0e38f;
#pragma unroll
    for (int nt = 0; nt < NT; ++nt) {
      float v = sc[nt][r];
      if (MASK) {
        const int col = colbase + nt * 16 + l15;
        v = (col <= row) ? v : -3.0e38f;
        sc[nt][r] = v;
      }
      best = fmaxf(best, v);
    }
    best = fmaxf(best, __shfl_xor(best, 1));
    best = fmaxf(best, __shfl_xor(best, 2));
    best = fmaxf(best, __shfl_xor(best, 4));
    best = fmaxf(best, __shfl_xor(best, 8));
    const float mnew = fmaxf(m_i[r], best);
    const float alpha = fast_exp2(m_i[r] - mnew);
    m_i[r] = mnew;
    float ls = 0.f;
#pragma unroll
    for (int nt = 0; nt < NT; ++nt) {
      const float p = fast_exp2(sc[nt][r] - mnew);
      sc[nt][r] = p;
      ls += p;
    }
    l_p[r] = l_p[r] * alpha + ls;  // lane-partial; reduced in epilogue
#pragma unroll
    for (int d = 0; d < 4; ++d) o[d][r] *= alpha;
  }
#pragma unroll
  for (int nt = 0; nt < NT; ++nt)
#pragma unroll
    for (int r = 0; r < 4; ++r)
      Psw[(4 * g + r) * 136 + nt * 16 + l15] = f2bf_trunc(sc[nt][r]);
  // PV (same-wave LDS write->read: no barrier)
#pragma unroll
  for (int ks = 0; ks < NT / 2; ++ks) {
    bf16x8 ap = *(const bf16x8*)&Psw[l15 * 136 + ks * 32 + 8 * g];
#pragma unroll
    for (int nt2 = 0; nt2 < 4; ++nt2) {
      const int rv = nt2 * 16 + l15;
      bf16x8 bv = *(const bf16x8*)&Vs[rv * 128 + (((ks * 4 + g) ^ (rv & 15)) * 8)];
      o[nt2] = __builtin_amdgcn_mfma_f32_16x16x32_bf16(ap, bv, o[nt2], 0, 0, 0);
    }
  }
}

__global__ __launch_bounds__(256) void attn_kernel(
    const unsigned short* __restrict__ q, const unsigned short* __restrict__ k,
    const unsigned short* __restrict__ vt, unsigned short* __restrict__ outp) {
  __shared__ __align__(16) unsigned short Ks[128 * 64];
  __shared__ __align__(16) unsigned short Vs[64 * 128];
  __shared__ __align__(16) unsigned short Ps[4][16 * 136];
  const int pb = blockIdx.x, bh = blockIdx.y;
  const int b = bh / H_, h = bh % H_;
  const unsigned short* qp = q + (size_t)bh * S_ * DK_;
  const unsigned short* kp = k + (size_t)bh * S_ * DK_;
  const unsigned short* vp = vt + (size_t)bh * DK_ * S_;
  const int tid = threadIdx.x, lane = tid & 63, w = tid >> 6;
  const int g = lane >> 4, l15 = lane & 15;

  for (int hv = 0; hv < 2; ++hv) {
    const int qb = hv ? (31 - pb) : pb;          // 64-row q-subtile index
    const int qrow = qb * 64 + w * 16 + l15;
    const bf16x8 aq0 = *(const bf16x8*)&qp[(size_t)qrow * DK_ + 8 * g];
    const bf16x8 aq1 = *(const bf16x8*)&qp[(size_t)qrow * DK_ + 32 + 8 * g];
    f32x4 o[4];
    float m_i[4], l_p[4];
    const f32x4 z = {0.f, 0.f, 0.f, 0.f};
#pragma unroll
    for (int r = 0; r < 4; ++r) { m_i[r] = -3.0e38f; l_p[r] = 0.f; o[r] = z; }
    const int rowg = qb * 64 + w * 16 + 4 * g;
    const int nkt = (qb >> 1) + 1;               // 128-key tiles

    for (int kt = 0; kt < nkt; ++kt) {
#pragma unroll
      for (int it = 0; it < 4; ++it) {
        const int idx = it * 256 + tid;
        const int rK = idx >> 3, cbK = (idx & 7) ^ (rK & 7);
        const int rV = idx >> 4, cbV = (idx & 15) ^ (rV & 15);
        const unsigned baseo =
            __builtin_amdgcn_readfirstlane((unsigned)((it * 256 + w * 64) * 8));
        GLOAD_LDS16(kp + ((size_t)kt * 128 + rK) * DK_ + cbK * 8, Ks + baseo);
        GLOAD_LDS16(vp + (size_t)rV * S_ + kt * 128 + cbV * 8, Vs + baseo);
      }
      __syncthreads();
      const int colbase = kt * 128;
      if (kt != nkt - 1)
        attn_tile<8, false>(Ks, Vs, &Ps[w][0], aq0, aq1, o, m_i, l_p, colbase, rowg, l15, g);
      else if (qb & 1)
        attn_tile<8, true>(Ks, Vs, &Ps[w][0], aq0, aq1, o, m_i, l_p, colbase, rowg, l15, g);
      else
        attn_tile<4, true>(Ks, Vs, &Ps[w][0], aq0, aq1, o, m_i, l_p, colbase, rowg, l15, g);
      __syncthreads();
    }
#pragma unroll
    for (int r = 0; r < 4; ++r) {
      float ls = l_p[r];
      ls += __shfl_xor(ls, 1);
      ls += __shfl_xor(ls, 2);
      ls += __shfl_xor(ls, 4);
      ls += __shfl_xor(ls, 8);
      l_p[r] = 1.0f / ls;
    }
#pragma unroll
    for (int nt2 = 0; nt2 < 4; ++nt2)
#pragma unroll
      for (int r = 0; r < 4; ++r) {
        const int s = qb * 64 + w * 16 + 4 * g + r;
        outp[((size_t)b * S_ + s) * D_ + h * 64 + nt2 * 16 + l15] =
            f2bf(o[nt2][r] * l_p[r]);
      }
  }
}

// ---------------------- fused Wg GEMM + bias + GeGLU -----------------------
// Dual accumulators (val+gate), BK=64.
__global__ __launch_bounds__(256, 2) void geglu_gemm(
    const unsigned short* __restrict__ A, const unsigned short* __restrict__ Bt,
    const float* __restrict__ bias, unsigned short* __restrict__ ff) {
  __shared__ __align__(16) unsigned short As[128 * 64];
  __shared__ __align__(16) unsigned short Bsv[128 * 64];
  __shared__ __align__(16) unsigned short Bsg[128 * 64];
  const int tid = threadIdx.x, lane = tid & 63, w = tid >> 6;
  const int wm = w >> 1, wn = w & 1, g = lane >> 4, l15 = lane & 15;
  const int m0 = blockIdx.x * 128, n0 = blockIdx.y * 128;
  const f32x4 z = {0.f, 0.f, 0.f, 0.f};
  f32x4 av[4][4], ag[4][4];
#pragma unroll
  for (int i = 0; i < 4; ++i)
#pragma unroll
    for (int j = 0; j < 4; ++j) { av[i][j] = z; ag[i][j] = z; }

  const unsigned short* Btg = Bt + (size_t)DFF_ * D_;

  for (int k0 = 0; k0 < D_; k0 += 64) {
#pragma unroll
    for (int it = 0; it < 4; ++it) {
      const int idx = it * 256 + tid;
      const int rr = idx >> 3, cc = (idx & 7) ^ (rr & 7);
      const unsigned baseo =
          __builtin_amdgcn_readfirstlane((unsigned)((it * 256 + w * 64) * 8));
      GLOAD_LDS16(A + (size_t)(m0 + rr) * D_ + k0 + cc * 8, As + baseo);
      GLOAD_LDS16(Bt + (size_t)(n0 + rr) * D_ + k0 + cc * 8, Bsv + baseo);
      GLOAD_LDS16(Btg + (size_t)(n0 + rr) * D_ + k0 + cc * 8, Bsg + baseo);
    }
    __syncthreads();
#pragma unroll
    for (int kh = 0; kh < 2; ++kh) {
      bf16x8 af[4], bv[4], bgf[4];
#pragma unroll
      for (int i = 0; i < 4; ++i) {
        const int rA = wm * 64 + i * 16 + l15;
        af[i] = *(const bf16x8*)&As[rA * 64 + (((kh * 4 + g) ^ (rA & 7)) * 8)];
      }
#pragma unroll
      for (int j = 0; j < 4; ++j) {
        const int rB = wn * 64 + j * 16 + l15;
        const int sw = ((kh * 4 + g) ^ (rB & 7)) * 8;
        bv[j] = *(const bf16x8*)&Bsv[rB * 64 + sw];
        bgf[j] = *(const bf16x8*)&Bsg[rB * 64 + sw];
      }
#pragma unroll
      for (int i = 0; i < 4; ++i)
#pragma unroll
        for (int j = 0; j < 4; ++j) {
          av[i][j] = __builtin_amdgcn_mfma_f32_16x16x32_bf16(af[i], bv[j], av[i][j], 0, 0, 0);
          ag[i][j] = __builtin_amdgcn_mfma_f32_16x16x32_bf16(af[i], bgf[j], ag[i][j], 0, 0, 0);
        }
    }
    __syncthreads();
  }

#pragma unroll
  for (int i = 0; i < 4; ++i)
#pragma unroll
    for (int j = 0; j < 4; ++j) {
      const int cl = wn * 64 + j * 16 + l15;
      const float bv_ = bias[n0 + cl], bg_ = bias[DFF_ + n0 + cl];
#pragma unroll
      for (int r = 0; r < 4; ++r) {
        const int rl = wm * 64 + i * 16 + 4 * g + r;
        const float val = av[i][j][r] + bv_;
        const float gate = ag[i][j][r] + bg_;
        const float ge = 0.5f * gate * (1.0f + erff(gate * 0.70710678118654752f));
        ff[(size_t)(m0 + rl) * DFF_ + n0 + cl] = f2bf(val * ge);
      }
    }
}

// ------------------------------- launcher ----------------------------------
extern "C" void kernel_launch(void* const* d_in, const int* in_sizes, int n_in,
                              void* d_out, int out_size, void* d_ws, size_t ws_size,
                              hipStream_t stream) {
  const float* x    = (const float*)d_in[0];
  const float* ln1g = (const float*)d_in[2];
  const float* ln1b = (const float*)d_in[3];
  const float* ln2g = (const float*)d_in[4];
  const float* ln2b = (const float*)d_in[5];
  const float* Wq   = (const float*)d_in[6];
  const float* Wk   = (const float*)d_in[7];
  const float* Wv   = (const float*)d_in[8];
  const float* Wo   = (const float*)d_in[9];
  const float* Wg   = (const float*)d_in[10];
  const float* bg   = (const float*)d_in[11];
  const float* Wout = (const float*)d_in[12];
  float* out = (float*)d_out;

  char* ws = (char*)d_ws;
  constexpr size_t SZ_WQKV = (size_t)3 * D_ * D_ * 2;
  constexpr size_t SZ_WO   = (size_t)D_ * D_ * 2;
  constexpr size_t SZ_WG   = (size_t)2 * DFF_ * D_ * 2;
  constexpr size_t SZ_WOUT = (size_t)D_ * DFF_ * 2;
  constexpr size_t SZ_ACT  = (size_t)B_ * S_ * D_ * 2;
  constexpr size_t OFF_WQKV = 0;
  constexpr size_t OFF_WO   = OFF_WQKV + SZ_WQKV;
  constexpr size_t OFF_WG   = OFF_WO + SZ_WO;
  constexpr size_t OFF_WOUT = OFF_WG + SZ_WG;
  constexpr size_t OFF_UNION = OFF_WOUT + SZ_WOUT;
  constexpr size_t OFF_H    = OFF_UNION;
  constexpr size_t OFF_Q    = OFF_UNION + SZ_ACT;
  constexpr size_t OFF_K    = OFF_UNION + 2 * SZ_ACT;
  constexpr size_t OFF_VT   = OFF_UNION + 3 * SZ_ACT;
  constexpr size_t OFF_FF   = OFF_UNION;               // ff overlays h/q/k/vt
  constexpr size_t OFF_ATTN = OFF_UNION + 4 * SZ_ACT;
  constexpr size_t OFF_X1   = OFF_ATTN + SZ_ACT;
  constexpr size_t OFF_H2   = OFF_X1 + (size_t)B_ * S_ * D_ * 4;

  unsigned short* wqkv_t = (unsigned short*)(ws + OFF_WQKV);
  unsigned short* wo_t   = (unsigned short*)(ws + OFF_WO);
  unsigned short* wg_t   = (unsigned short*)(ws + OFF_WG);
  unsigned short* wout_t = (unsigned short*)(ws + OFF_WOUT);
  unsigned short* h    = (unsigned short*)(ws + OFF_H);
  unsigned short* qb_  = (unsigned short*)(ws + OFF_Q);
  unsigned short* kb_  = (unsigned short*)(ws + OFF_K);
  unsigned short* vtb_ = (unsigned short*)(ws + OFF_VT);
  unsigned short* attn = (unsigned short*)(ws + OFF_ATTN);
  float*          x1   = (float*)(ws + OFF_X1);
  unsigned short* h2   = (unsigned short*)(ws + OFF_H2);
  unsigned short* ffb  = (unsigned short*)(ws + OFF_FF);

  {
    TransArgs a;
    a.s[0] = Wq; a.s[1] = Wk; a.s[2] = Wv; a.s[3] = Wo;
    a.d[0] = wqkv_t; a.d[1] = wqkv_t + (size_t)D_ * D_;
    a.d[2] = wqkv_t + (size_t)2 * D_ * D_; a.d[3] = wo_t;
    transpose_cvt<<<dim3(24, 24, 4), 256, 0, stream>>>(a, D_, D_);
    TransArgs agr; agr.s[0] = Wg; agr.d[0] = wg_t;
    agr.s[1] = agr.s[2] = agr.s[3] = Wg; agr.d[1] = agr.d[2] = agr.d[3] = wg_t;
    transpose_cvt<<<dim3(24, 192, 1), 256, 0, stream>>>(agr, D_, 2 * DFF_);
    TransArgs ao; ao.s[0] = Wout; ao.d[0] = wout_t;
    ao.s[1] = ao.s[2] = ao.s[3] = Wout; ao.d[1] = ao.d[2] = ao.d[3] = wout_t;
    transpose_cvt<<<dim3(96, 24, 1), 256, 0, stream>>>(ao, DFF_, D_);
  }

  ln_kernel<<<dim3(B_ * S_ / 4), 256, 0, stream>>>(x, ln1g, ln1b, h);
  gemm_bt<EP_QKV><<<dim3(64, 18), 256, 0, stream>>>(h, wqkv_t, B_ * S_, 3 * D_, D_,
                                                    nullptr, nullptr, qb_, kb_, vtb_);
  attn_kernel<<<dim3(16, B_ * H_), 256, 0, stream>>>(qb_, kb_, vtb_, attn);
  gemm_bt64<<<dim3(128, 6), 256, 0, stream>>>(attn, wo_t, B_ * S_, D_, D_, x1, x);
  ln_kernel<<<dim3(B_ * S_ / 4), 256, 0, stream>>>(x1, ln2g, ln2b, h2);
  geglu_gemm<<<dim3(64, 24), 256, 0, stream>>>(h2, wg_t, bg, ffb);
  gemm_bt64<<<dim3(128, 6), 256, 0, stream>>>(ffb, wout_t, B_ * S_, D_, DFF_, out, x1);
}